// Round 1
// baseline (229.243 us; speedup 1.0000x reference)
//
#include <hip/hip_runtime.h>

// Problem constants (setup_inputs is fixed: 48x48 input, 192x192 output, factor=4)
#define NXY   48
#define NG    2304      // 48*48 gaussians
#define CFE   32        // conv output channels
#define KDIM  288       // 32*9 unfolded feature dim
#define HID   256
#define NHID  1024      // 4 heads * 256
#define HW    192
#define NPIX  (HW*HW)   // 36864

// ---------------- conv 3x3 SAME, NCHW, correlation (lax conv) ----------------
__global__ __launch_bounds__(256) void conv_k(const float* __restrict__ inp,
                                              const float* __restrict__ cw,
                                              const float* __restrict__ cb,
                                              float* __restrict__ feat) {
    int idx = blockIdx.x * 256 + threadIdx.x;   // c*2304 + h*48 + w
    if (idx >= CFE * NXY * NXY) return;
    int w = idx % NXY, h = (idx / NXY) % NXY, o = idx / (NXY * NXY);
    float acc = cb[o];
    #pragma unroll
    for (int i = 0; i < 3; ++i) {
        #pragma unroll
        for (int kh = 0; kh < 3; ++kh) {
            int hh = h + kh - 1;
            if (hh < 0 || hh >= NXY) continue;
            #pragma unroll
            for (int kw = 0; kw < 3; ++kw) {
                int ww = w + kw - 1;
                if (ww < 0 || ww >= NXY) continue;
                acc = fmaf(inp[(i * NXY + hh) * NXY + ww],
                           cw[((o * 3 + i) * 3 + kh) * 3 + kw], acc);
            }
        }
    }
    feat[idx] = acc;
}

// --------- unfold 3x3 + LayerNorm over 288, one 64-lane wave per gaussian ----
// feature[n=(x,y)][c*9+ki*3+kj] = feat[c][h=y+kj-1][w=x+ki-1] (zero-padded)
__global__ __launch_bounds__(64) void ln_k(const float* __restrict__ feat,
                                           float* __restrict__ fln) {
    int n = blockIdx.x;
    int lane = threadIdx.x;
    int x = n / NXY, y = n % NXY;
    float v[5];
    float sum = 0.f, sq = 0.f;
    #pragma unroll
    for (int i = 0; i < 5; ++i) {
        int k = lane + 64 * i;
        float val = 0.f;
        if (k < KDIM) {
            int c = k / 9, r = k % 9, ki = r / 3, kj = r % 3;
            int hh = y + kj - 1, ww = x + ki - 1;
            if (hh >= 0 && hh < NXY && ww >= 0 && ww < NXY)
                val = feat[(c * NXY + hh) * NXY + ww];
        }
        v[i] = val; sum += val; sq = fmaf(val, val, sq);
    }
    #pragma unroll
    for (int off = 32; off; off >>= 1) {
        sum += __shfl_xor(sum, off);
        sq  += __shfl_xor(sq,  off);
    }
    float mean = sum * (1.0f / KDIM);
    float var  = sq * (1.0f / KDIM) - mean * mean;
    float rstd = rsqrtf(var + 1e-5f);
    #pragma unroll
    for (int i = 0; i < 5; ++i) {
        int k = lane + 64 * i;
        if (k < KDIM) fln[n * KDIM + k] = (v[i] - mean) * rstd;
    }
}

// ---- fp32 GEMM: [2304 x 288] @ [288 x 1024] (+bias, ReLU) -> hidden --------
// 4 head W1 matrices selected per 64-col tile (256 % 64 == 0).
__global__ __launch_bounds__(256) void gemm_k(const float* __restrict__ A,
        const float* __restrict__ w1_0, const float* __restrict__ w1_1,
        const float* __restrict__ w1_2, const float* __restrict__ w1_3,
        const float* __restrict__ b1_0, const float* __restrict__ b1_1,
        const float* __restrict__ b1_2, const float* __restrict__ b1_3,
        float* __restrict__ Hout) {
    __shared__ float As[16][64];
    __shared__ float Bs[16][64];
    int tid = threadIdx.x;
    int m0    = blockIdx.x * 64;
    int ncol0 = blockIdx.y * 64;
    int head  = ncol0 >> 8;
    int colh  = ncol0 & 255;
    const float* Bw = head == 0 ? w1_0 : head == 1 ? w1_1 : head == 2 ? w1_2 : w1_3;
    const float* bb = head == 0 ? b1_0 : head == 1 ? b1_1 : head == 2 ? b1_2 : b1_3;
    int tx = tid & 15, ty = tid >> 4;
    int kkA = tid & 15, mmA = tid >> 4;
    int nnB = tid & 63, kkB = tid >> 6;
    float acc[4][4] = {};
    for (int k0 = 0; k0 < KDIM; k0 += 16) {
        #pragma unroll
        for (int r = 0; r < 4; ++r)
            As[kkA][mmA + 16 * r] = A[(m0 + mmA + 16 * r) * KDIM + k0 + kkA];
        #pragma unroll
        for (int r = 0; r < 4; ++r)
            Bs[kkB + 4 * r][nnB] = Bw[(k0 + kkB + 4 * r) * HID + colh + nnB];
        __syncthreads();
        #pragma unroll
        for (int kk = 0; kk < 16; ++kk) {
            float4 av = *(const float4*)&As[kk][ty * 4];
            float4 bv = *(const float4*)&Bs[kk][tx * 4];
            float a[4] = {av.x, av.y, av.z, av.w};
            float b[4] = {bv.x, bv.y, bv.z, bv.w};
            #pragma unroll
            for (int i = 0; i < 4; ++i)
                #pragma unroll
                for (int j = 0; j < 4; ++j)
                    acc[i][j] = fmaf(a[i], b[j], acc[i][j]);
        }
        __syncthreads();
    }
    #pragma unroll
    for (int i = 0; i < 4; ++i) {
        int row = m0 + ty * 4 + i;
        #pragma unroll
        for (int j = 0; j < 4; ++j) {
            float v = acc[i][j] + bb[colh + tx * 4 + j];
            Hout[row * NHID + ncol0 + tx * 4 + j] = fmaxf(v, 0.0f);
        }
    }
}

// ------- per-gaussian: 8 head dots (256 each), activations, conic -----------
// gp[n][8] = {cx_pix, cy_pix, 0.5*conicA, conicB, 0.5*conicC, r, g, b}
__global__ __launch_bounds__(256) void head_k(const float* __restrict__ Hh,
        const float* __restrict__ ow2, const float* __restrict__ ob2,
        const float* __restrict__ sw2, const float* __restrict__ sb2,
        const float* __restrict__ rw2, const float* __restrict__ rb2,
        const float* __restrict__ cw2, const float* __restrict__ cb2,
        float* __restrict__ gp) {
    int tid = threadIdx.x;
    int lane = tid & 63, wv = tid >> 6;
    int n = blockIdx.x * 4 + wv;
    const float* h = Hh + n * NHID;
    float s[8] = {};
    #pragma unroll
    for (int i = 0; i < 4; ++i) {
        int j = lane + 64 * i;
        float h0 = h[j], h1 = h[256 + j], h2 = h[512 + j], h3 = h[768 + j];
        s[0] = fmaf(h0, ow2[j * 2 + 0], s[0]);
        s[1] = fmaf(h0, ow2[j * 2 + 1], s[1]);
        s[2] = fmaf(h1, sw2[j * 2 + 0], s[2]);
        s[3] = fmaf(h1, sw2[j * 2 + 1], s[3]);
        s[4] = fmaf(h2, rw2[j],         s[4]);
        s[5] = fmaf(h3, cw2[j * 3 + 0], s[5]);
        s[6] = fmaf(h3, cw2[j * 3 + 1], s[6]);
        s[7] = fmaf(h3, cw2[j * 3 + 2], s[7]);
    }
    #pragma unroll
    for (int off = 32; off; off >>= 1)
        #pragma unroll
        for (int k = 0; k < 8; ++k) s[k] += __shfl_xor(s[k], off);
    if (lane == 0) {
        float o0 = s[0] + ob2[0], o1 = s[1] + ob2[1];
        float z0 = s[2] + sb2[0], z1 = s[3] + sb2[1];
        float zr = s[4] + rb2[0];
        float c0 = s[5] + cb2[0], c1 = s[6] + cb2[1], c2 = s[7] + cb2[2];
        int x = n / NXY, y = n % NXY;
        // off_factor = 2*4/192 -> offset = tanh*3*off_factor = tanh*0.125
        float ndcx = ((x + 0.5f) * (2.0f / NXY) - 1.0f) + tanhf(o0) * 0.125f;
        float ndcy = ((y + 0.5f) * (2.0f / NXY) - 1.0f) + tanhf(o1) * 0.125f;
        float cxp = 0.5f * ((ndcx + 1.0f) * HW - 1.0f);
        float cyp = 0.5f * ((ndcy + 1.0f) * HW - 1.0f);
        float sx = 8.0f / (1.0f + expf(-z0));   // sigmoid * 2 * factor
        float sy = 8.0f / (1.0f + expf(-z1));
        float rot = 6.283185307179586f / (1.0f + expf(-zr));
        float cc = cosf(rot), ss = sinf(rot);
        float sx2 = sx * sx, sy2 = sy * sy;
        float cov00 = cc * cc * sx2 + ss * ss * sy2;
        float cov01 = cc * ss * (sx2 - sy2);
        float cov11 = ss * ss * sx2 + cc * cc * sy2;
        float det = cov00 * cov11 - cov01 * cov01;
        float inv = 1.0f / det;
        float A = cov11 * inv, Bc = -cov01 * inv, Cc = cov00 * inv;
        float4* dst = (float4*)&gp[n * 8];
        dst[0] = make_float4(cxp, cyp, 0.5f * A, Bc);
        dst[1] = make_float4(0.5f * Cc, tanhf(c0), tanhf(c1), tanhf(c2));
    }
}

// --------------- render: 16x16 pixel tile per block, LDS-staged -------------
__global__ __launch_bounds__(256) void render_k(const float* __restrict__ gp,
                                                float* __restrict__ out) {
    __shared__ float4 gs[256][2];
    int wpix = blockIdx.x * 16 + threadIdx.x;
    int hpix = blockIdx.y * 16 + threadIdx.y;
    float px = (float)wpix, py = (float)hpix;
    float ar = 0.f, ag = 0.f, ab = 0.f;
    int t = threadIdx.y * 16 + threadIdx.x;
    for (int g0 = 0; g0 < NG; g0 += 256) {
        const float4* src = (const float4*)&gp[(g0 + t) * 8];
        gs[t][0] = src[0];
        gs[t][1] = src[1];
        __syncthreads();
        for (int gg = 0; gg < 256; ++gg) {
            float4 p0 = gs[gg][0];
            float4 p1 = gs[gg][1];
            float dx = px - p0.x;
            float dy = py - p0.y;
            // sigma = 0.5*A dx^2 + B dx dy + 0.5*C dy^2 (halves pre-folded)
            float sigma = fmaf(dx, fmaf(p0.z, dx, p0.w * dy), p1.x * dy * dy);
            if (sigma <= 5.6f) {                       // ln(255) = 5.5413
                float a = __expf(-sigma);
                if (a >= (1.0f / 255.0f)) {
                    ar = fmaf(a, p1.y, ar);
                    ag = fmaf(a, p1.z, ag);
                    ab = fmaf(a, p1.w, ab);
                }
            }
        }
        __syncthreads();
    }
    int pix = hpix * HW + wpix;
    out[pix]            = fminf(fmaxf(ar, 0.f), 1.f);
    out[NPIX + pix]     = fminf(fmaxf(ag, 0.f), 1.f);
    out[2 * NPIX + pix] = fminf(fmaxf(ab, 0.f), 1.f);
}

extern "C" void kernel_launch(void* const* d_in, const int* in_sizes, int n_in,
                              void* d_out, int out_size, void* d_ws, size_t ws_size,
                              hipStream_t stream) {
    const float* inp = (const float*)d_in[0];
    const float* cw  = (const float*)d_in[1];
    const float* cb  = (const float*)d_in[2];
    const float* ow1 = (const float*)d_in[3];
    const float* ob1 = (const float*)d_in[4];
    const float* ow2 = (const float*)d_in[5];
    const float* ob2 = (const float*)d_in[6];
    const float* sw1 = (const float*)d_in[7];
    const float* sb1 = (const float*)d_in[8];
    const float* sw2 = (const float*)d_in[9];
    const float* sb2 = (const float*)d_in[10];
    const float* rw1 = (const float*)d_in[11];
    const float* rb1 = (const float*)d_in[12];
    const float* rw2 = (const float*)d_in[13];
    const float* rb2 = (const float*)d_in[14];
    const float* cw1 = (const float*)d_in[15];
    const float* cb1 = (const float*)d_in[16];
    const float* cw2 = (const float*)d_in[17];
    const float* cb2 = (const float*)d_in[18];

    float* ws   = (float*)d_ws;
    float* feat = ws;                 // 73728
    float* fln  = ws + 73728;         // 663552
    float* hid  = ws + 737280;        // 2359296
    float* gpar = ws + 3096576;       // 18432
    float* out  = (float*)d_out;

    hipLaunchKernelGGL(conv_k, dim3(288), dim3(256), 0, stream, inp, cw, cb, feat);
    hipLaunchKernelGGL(ln_k, dim3(NG), dim3(64), 0, stream, feat, fln);
    hipLaunchKernelGGL(gemm_k, dim3(36, 16), dim3(256), 0, stream,
                       fln, ow1, sw1, rw1, cw1, ob1, sb1, rb1, cb1, hid);
    hipLaunchKernelGGL(head_k, dim3(576), dim3(256), 0, stream,
                       hid, ow2, ob2, sw2, sb2, rw2, rb2, cw2, cb2, gpar);
    hipLaunchKernelGGL(render_k, dim3(12, 12), dim3(16, 16), 0, stream, gpar, out);
}

// Round 2
// 66.062 us; speedup vs baseline: 3.4701x; 3.4701x over previous
//
#include <hip/hip_runtime.h>

// Problem constants (setup_inputs is fixed: 48x48 input, 192x192 output, factor=4)
#define NXY   48
#define NG    2304      // 48*48 gaussians
#define CFE   32        // conv output channels
#define KDIM  288       // 32*9 unfolded feature dim
#define HID   256
#define NHID  1024      // 4 heads * 256
#define HW    192
#define NPIX  (HW*HW)   // 36864
#define NCHUNK (NG/64)  // 36 gaussian chunks of 64

// ---------------- conv 3x3 SAME, NCHW, correlation (lax conv) ----------------
__global__ __launch_bounds__(256) void conv_k(const float* __restrict__ inp,
                                              const float* __restrict__ cw,
                                              const float* __restrict__ cb,
                                              float* __restrict__ feat) {
    int idx = blockIdx.x * 256 + threadIdx.x;   // c*2304 + h*48 + w
    if (idx >= CFE * NXY * NXY) return;
    int w = idx % NXY, h = (idx / NXY) % NXY, o = idx / (NXY * NXY);
    float acc = cb[o];
    #pragma unroll
    for (int i = 0; i < 3; ++i) {
        #pragma unroll
        for (int kh = 0; kh < 3; ++kh) {
            int hh = h + kh - 1;
            if (hh < 0 || hh >= NXY) continue;
            #pragma unroll
            for (int kw = 0; kw < 3; ++kw) {
                int ww = w + kw - 1;
                if (ww < 0 || ww >= NXY) continue;
                acc = fmaf(inp[(i * NXY + hh) * NXY + ww],
                           cw[((o * 3 + i) * 3 + kh) * 3 + kw], acc);
            }
        }
    }
    feat[idx] = acc;
}

// --------- unfold 3x3 + LayerNorm over 288, one 64-lane wave per gaussian ----
// feature[n=(x,y)][c*9+ki*3+kj] = feat[c][h=y+kj-1][w=x+ki-1] (zero-padded)
__global__ __launch_bounds__(64) void ln_k(const float* __restrict__ feat,
                                           float* __restrict__ fln) {
    int n = blockIdx.x;
    int lane = threadIdx.x;
    int x = n / NXY, y = n % NXY;
    float v[5];
    float sum = 0.f, sq = 0.f;
    #pragma unroll
    for (int i = 0; i < 5; ++i) {
        int k = lane + 64 * i;
        float val = 0.f;
        if (k < KDIM) {
            int c = k / 9, r = k % 9, ki = r / 3, kj = r % 3;
            int hh = y + kj - 1, ww = x + ki - 1;
            if (hh >= 0 && hh < NXY && ww >= 0 && ww < NXY)
                val = feat[(c * NXY + hh) * NXY + ww];
        }
        v[i] = val; sum += val; sq = fmaf(val, val, sq);
    }
    #pragma unroll
    for (int off = 32; off; off >>= 1) {
        sum += __shfl_xor(sum, off);
        sq  += __shfl_xor(sq,  off);
    }
    float mean = sum * (1.0f / KDIM);
    float var  = sq * (1.0f / KDIM) - mean * mean;
    float rstd = rsqrtf(var + 1e-5f);
    #pragma unroll
    for (int i = 0; i < 5; ++i) {
        int k = lane + 64 * i;
        if (k < KDIM) fln[n * KDIM + k] = (v[i] - mean) * rstd;
    }
}

// ---- fp32 GEMM: [2304 x 288] @ [288 x 1024] (+bias, ReLU) -> hidden --------
// 4 head W1 matrices selected per 64-col tile (256 % 64 == 0).
__global__ __launch_bounds__(256) void gemm_k(const float* __restrict__ A,
        const float* __restrict__ w1_0, const float* __restrict__ w1_1,
        const float* __restrict__ w1_2, const float* __restrict__ w1_3,
        const float* __restrict__ b1_0, const float* __restrict__ b1_1,
        const float* __restrict__ b1_2, const float* __restrict__ b1_3,
        float* __restrict__ Hout) {
    __shared__ float As[16][64];
    __shared__ float Bs[16][64];
    int tid = threadIdx.x;
    int m0    = blockIdx.x * 64;
    int ncol0 = blockIdx.y * 64;
    int head  = ncol0 >> 8;
    int colh  = ncol0 & 255;
    const float* Bw = head == 0 ? w1_0 : head == 1 ? w1_1 : head == 2 ? w1_2 : w1_3;
    const float* bb = head == 0 ? b1_0 : head == 1 ? b1_1 : head == 2 ? b1_2 : b1_3;
    int tx = tid & 15, ty = tid >> 4;
    int kkA = tid & 15, mmA = tid >> 4;
    int nnB = tid & 63, kkB = tid >> 6;
    float acc[4][4] = {};
    for (int k0 = 0; k0 < KDIM; k0 += 16) {
        #pragma unroll
        for (int r = 0; r < 4; ++r)
            As[kkA][mmA + 16 * r] = A[(m0 + mmA + 16 * r) * KDIM + k0 + kkA];
        #pragma unroll
        for (int r = 0; r < 4; ++r)
            Bs[kkB + 4 * r][nnB] = Bw[(k0 + kkB + 4 * r) * HID + colh + nnB];
        __syncthreads();
        #pragma unroll
        for (int kk = 0; kk < 16; ++kk) {
            float4 av = *(const float4*)&As[kk][ty * 4];
            float4 bv = *(const float4*)&Bs[kk][tx * 4];
            float a[4] = {av.x, av.y, av.z, av.w};
            float b[4] = {bv.x, bv.y, bv.z, bv.w};
            #pragma unroll
            for (int i = 0; i < 4; ++i)
                #pragma unroll
                for (int j = 0; j < 4; ++j)
                    acc[i][j] = fmaf(a[i], b[j], acc[i][j]);
        }
        __syncthreads();
    }
    #pragma unroll
    for (int i = 0; i < 4; ++i) {
        int row = m0 + ty * 4 + i;
        #pragma unroll
        for (int j = 0; j < 4; ++j) {
            float v = acc[i][j] + bb[colh + tx * 4 + j];
            Hout[row * NHID + ncol0 + tx * 4 + j] = fmaxf(v, 0.0f);
        }
    }
}

// ------- per-gaussian: 8 head dots (256 each), activations, conic, bbox -----
// gbox[n] = {cx_pix, cy_pix, rx, ry}; gdat[2n]={0.5A, B, 0.5C, r}; gdat[2n+1]={g, b, 0, 0}
__global__ __launch_bounds__(256) void head_k(const float* __restrict__ Hh,
        const float* __restrict__ ow2, const float* __restrict__ ob2,
        const float* __restrict__ sw2, const float* __restrict__ sb2,
        const float* __restrict__ rw2, const float* __restrict__ rb2,
        const float* __restrict__ cw2, const float* __restrict__ cb2,
        float4* __restrict__ gbox, float4* __restrict__ gdat) {
    int tid = threadIdx.x;
    int lane = tid & 63, wv = tid >> 6;
    int n = blockIdx.x * 4 + wv;
    const float* h = Hh + n * NHID;
    float s[8] = {};
    #pragma unroll
    for (int i = 0; i < 4; ++i) {
        int j = lane + 64 * i;
        float h0 = h[j], h1 = h[256 + j], h2 = h[512 + j], h3 = h[768 + j];
        s[0] = fmaf(h0, ow2[j * 2 + 0], s[0]);
        s[1] = fmaf(h0, ow2[j * 2 + 1], s[1]);
        s[2] = fmaf(h1, sw2[j * 2 + 0], s[2]);
        s[3] = fmaf(h1, sw2[j * 2 + 1], s[3]);
        s[4] = fmaf(h2, rw2[j],         s[4]);
        s[5] = fmaf(h3, cw2[j * 3 + 0], s[5]);
        s[6] = fmaf(h3, cw2[j * 3 + 1], s[6]);
        s[7] = fmaf(h3, cw2[j * 3 + 2], s[7]);
    }
    #pragma unroll
    for (int off = 32; off; off >>= 1)
        #pragma unroll
        for (int k = 0; k < 8; ++k) s[k] += __shfl_xor(s[k], off);
    if (lane == 0) {
        float o0 = s[0] + ob2[0], o1 = s[1] + ob2[1];
        float z0 = s[2] + sb2[0], z1 = s[3] + sb2[1];
        float zr = s[4] + rb2[0];
        float c0 = s[5] + cb2[0], c1 = s[6] + cb2[1], c2 = s[7] + cb2[2];
        int x = n / NXY, y = n % NXY;
        // off_factor = 2*4/192 -> offset = tanh*3*off_factor = tanh*0.125
        float ndcx = ((x + 0.5f) * (2.0f / NXY) - 1.0f) + tanhf(o0) * 0.125f;
        float ndcy = ((y + 0.5f) * (2.0f / NXY) - 1.0f) + tanhf(o1) * 0.125f;
        float cxp = 0.5f * ((ndcx + 1.0f) * HW - 1.0f);
        float cyp = 0.5f * ((ndcy + 1.0f) * HW - 1.0f);
        float sx = 8.0f / (1.0f + expf(-z0));   // sigmoid * 2 * factor
        float sy = 8.0f / (1.0f + expf(-z1));
        float rot = 6.283185307179586f / (1.0f + expf(-zr));
        float cc = cosf(rot), ss = sinf(rot);
        float sx2 = sx * sx, sy2 = sy * sy;
        float cov00 = cc * cc * sx2 + ss * ss * sy2;
        float cov01 = cc * ss * (sx2 - sy2);
        float cov11 = ss * ss * sx2 + cc * cc * sy2;
        float det = cov00 * cov11 - cov01 * cov01;
        float inv = 1.0f / det;
        float A = cov11 * inv, Bc = -cov01 * inv, Cc = cov00 * inv;
        // bbox of the {alpha >= 1/255} ellipse: |dx| <= sqrt(2*tau*cov00),
        // tau = ln255 = 5.5413; use 5.6 + eps margin for fp safety.
        float rx = sqrtf(11.2f * cov00) + 1e-2f;
        float ry = sqrtf(11.2f * cov11) + 1e-2f;
        gbox[n]         = make_float4(cxp, cyp, rx, ry);
        gdat[2 * n]     = make_float4(0.5f * A, Bc, 0.5f * Cc, tanhf(c0));
        gdat[2 * n + 1] = make_float4(tanhf(c1), tanhf(c2), 0.f, 0.f);
    }
}

// --------------- render: 8x8 pixel tile, 4 waves split gaussians, culled ----
__global__ __launch_bounds__(256) void render_k(const float4* __restrict__ gbox,
                                                const float4* __restrict__ gdat,
                                                float* __restrict__ out) {
    __shared__ float4 ldsE[4][64][2];   // per-wave compacted survivor list
    __shared__ float red[4][64][3];     // cross-wave reduction
    int lane = threadIdx.x & 63;
    int wv   = threadIdx.x >> 6;
    int tx0 = blockIdx.x * 8, ty0 = blockIdx.y * 8;
    float px = (float)(tx0 + (lane & 7));
    float py = (float)(ty0 + (lane >> 3));
    float xlo = (float)tx0, xhi = (float)(tx0 + 7);
    float ylo = (float)ty0, yhi = (float)(ty0 + 7);
    float ar = 0.f, ag = 0.f, ab = 0.f;
    for (int c = wv; c < NCHUNK; c += 4) {
        int g = c * 64 + lane;
        float4 bb = gbox[g];
        bool pred = (bb.x - bb.z <= xhi) && (bb.x + bb.z >= xlo) &&
                    (bb.y - bb.w <= yhi) && (bb.y + bb.w >= ylo);
        unsigned long long m = __ballot(pred);
        int cnt = __popcll(m);
        int pos = __popcll(m & ((1ull << lane) - 1ull));
        if (pred) {
            float4 d0 = gdat[2 * g];
            float4 d1 = gdat[2 * g + 1];
            ldsE[wv][pos][0] = make_float4(bb.x, bb.y, d0.x, d0.y);  // cx cy .5A B
            ldsE[wv][pos][1] = make_float4(d0.z, d0.w, d1.x, d1.y);  // .5C r g b
        }
        __syncthreads();   // orders LDS writes vs reads (uniform trip count)
        for (int i = 0; i < cnt; ++i) {
            float4 e0 = ldsE[wv][i][0];
            float4 e1 = ldsE[wv][i][1];
            float dx = px - e0.x;
            float dy = py - e0.y;
            float sigma = fmaf(dx, fmaf(e0.z, dx, e0.w * dy), e1.x * dy * dy);
            float a = __expf(-sigma);
            a = (a >= (1.0f / 255.0f)) ? a : 0.f;
            ar = fmaf(a, e1.y, ar);
            ag = fmaf(a, e1.z, ag);
            ab = fmaf(a, e1.w, ab);
        }
        __syncthreads();
    }
    red[wv][lane][0] = ar; red[wv][lane][1] = ag; red[wv][lane][2] = ab;
    __syncthreads();
    if (wv == 0) {
        float r_ = red[0][lane][0] + red[1][lane][0] + red[2][lane][0] + red[3][lane][0];
        float g_ = red[0][lane][1] + red[1][lane][1] + red[2][lane][1] + red[3][lane][1];
        float b_ = red[0][lane][2] + red[1][lane][2] + red[2][lane][2] + red[3][lane][2];
        int pix = (ty0 + (lane >> 3)) * HW + tx0 + (lane & 7);
        out[pix]            = fminf(fmaxf(r_, 0.f), 1.f);
        out[NPIX + pix]     = fminf(fmaxf(g_, 0.f), 1.f);
        out[2 * NPIX + pix] = fminf(fmaxf(b_, 0.f), 1.f);
    }
}

extern "C" void kernel_launch(void* const* d_in, const int* in_sizes, int n_in,
                              void* d_out, int out_size, void* d_ws, size_t ws_size,
                              hipStream_t stream) {
    const float* inp = (const float*)d_in[0];
    const float* cw  = (const float*)d_in[1];
    const float* cb  = (const float*)d_in[2];
    const float* ow1 = (const float*)d_in[3];
    const float* ob1 = (const float*)d_in[4];
    const float* ow2 = (const float*)d_in[5];
    const float* ob2 = (const float*)d_in[6];
    const float* sw1 = (const float*)d_in[7];
    const float* sb1 = (const float*)d_in[8];
    const float* sw2 = (const float*)d_in[9];
    const float* sb2 = (const float*)d_in[10];
    const float* rw1 = (const float*)d_in[11];
    const float* rb1 = (const float*)d_in[12];
    const float* rw2 = (const float*)d_in[13];
    const float* rb2 = (const float*)d_in[14];
    const float* cw1 = (const float*)d_in[15];
    const float* cb1 = (const float*)d_in[16];
    const float* cw2 = (const float*)d_in[17];
    const float* cb2 = (const float*)d_in[18];

    float* ws   = (float*)d_ws;
    float* feat = ws;                 // 73728
    float* fln  = ws + 73728;         // 663552
    float* hid  = ws + 737280;        // 2359296
    float4* gbox = (float4*)(ws + 3096576);          // 2304 float4
    float4* gdat = (float4*)(ws + 3096576 + 9216);   // 4608 float4
    float* out  = (float*)d_out;

    hipLaunchKernelGGL(conv_k, dim3(288), dim3(256), 0, stream, inp, cw, cb, feat);
    hipLaunchKernelGGL(ln_k, dim3(NG), dim3(64), 0, stream, feat, fln);
    hipLaunchKernelGGL(gemm_k, dim3(36, 16), dim3(256), 0, stream,
                       fln, ow1, sw1, rw1, cw1, ob1, sb1, rb1, cb1, hid);
    hipLaunchKernelGGL(head_k, dim3(576), dim3(256), 0, stream,
                       hid, ow2, ob2, sw2, sb2, rw2, rb2, cw2, cb2, gbox, gdat);
    hipLaunchKernelGGL(render_k, dim3(24, 24), dim3(256), 0, stream, gbox, gdat, out);
}

// Round 3
// 53.189 us; speedup vs baseline: 4.3100x; 1.2420x over previous
//
#include <hip/hip_runtime.h>

// Problem constants (setup_inputs is fixed: 48x48 input, 192x192 output, factor=4)
#define NXY   48
#define NG    2304      // 48*48 gaussians
#define CFE   32        // conv output channels
#define KDIM  288       // 32*9 unfolded feature dim
#define HID   256
#define NHID  1024      // 4 heads * 256
#define HW    192
#define NPIX  (HW*HW)   // 36864
#define NCHUNK (NG/64)  // 36 gaussian chunks of 64

typedef __bf16 bf16x8 __attribute__((ext_vector_type(8)));
typedef float  f32x4  __attribute__((ext_vector_type(4)));
typedef unsigned short ushort_t;
typedef unsigned int   uint_t;

__device__ __forceinline__ ushort_t f2bf(float x) {          // RNE float->bf16 bits
    uint_t u = __float_as_uint(x);
    uint_t r = u + 0x7FFFu + ((u >> 16) & 1u);
    return (ushort_t)(r >> 16);
}
__device__ __forceinline__ float bf2f(ushort_t h) {
    return __uint_as_float(((uint_t)h) << 16);
}

// ---------------- conv 3x3 SAME, NCHW, correlation (lax conv) ----------------
__global__ __launch_bounds__(256) void conv_k(const float* __restrict__ inp,
                                              const float* __restrict__ cw,
                                              const float* __restrict__ cb,
                                              float* __restrict__ feat) {
    int idx = blockIdx.x * 256 + threadIdx.x;   // c*2304 + h*48 + w
    if (idx >= CFE * NXY * NXY) return;
    int w = idx % NXY, h = (idx / NXY) % NXY, o = idx / (NXY * NXY);
    float acc = cb[o];
    #pragma unroll
    for (int i = 0; i < 3; ++i) {
        #pragma unroll
        for (int kh = 0; kh < 3; ++kh) {
            int hh = h + kh - 1;
            if (hh < 0 || hh >= NXY) continue;
            #pragma unroll
            for (int kw = 0; kw < 3; ++kw) {
                int ww = w + kw - 1;
                if (ww < 0 || ww >= NXY) continue;
                acc = fmaf(inp[(i * NXY + hh) * NXY + ww],
                           cw[((o * 3 + i) * 3 + kh) * 3 + kw], acc);
            }
        }
    }
    feat[idx] = acc;
}

// --------- unfold 3x3 + LayerNorm over 288 -> split bf16 (hi, lo) -----------
// feature[n=(x,y)][c*9+ki*3+kj] = feat[c][h=y+kj-1][w=x+ki-1] (zero-padded)
__global__ __launch_bounds__(64) void ln_k(const float* __restrict__ feat,
                                           ushort_t* __restrict__ Ahi,
                                           ushort_t* __restrict__ Alo) {
    int n = blockIdx.x;
    int lane = threadIdx.x;
    int x = n / NXY, y = n % NXY;
    float v[5];
    float sum = 0.f, sq = 0.f;
    #pragma unroll
    for (int i = 0; i < 5; ++i) {
        int k = lane + 64 * i;
        float val = 0.f;
        if (k < KDIM) {
            int c = k / 9, r = k % 9, ki = r / 3, kj = r % 3;
            int hh = y + kj - 1, ww = x + ki - 1;
            if (hh >= 0 && hh < NXY && ww >= 0 && ww < NXY)
                val = feat[(c * NXY + hh) * NXY + ww];
        }
        v[i] = val; sum += val; sq = fmaf(val, val, sq);
    }
    #pragma unroll
    for (int off = 32; off; off >>= 1) {
        sum += __shfl_xor(sum, off);
        sq  += __shfl_xor(sq,  off);
    }
    float mean = sum * (1.0f / KDIM);
    float var  = sq * (1.0f / KDIM) - mean * mean;
    float rstd = rsqrtf(var + 1e-5f);
    #pragma unroll
    for (int i = 0; i < 5; ++i) {
        int k = lane + 64 * i;
        if (k < KDIM) {
            float w = (v[i] - mean) * rstd;
            ushort_t hb = f2bf(w);
            ushort_t lb = f2bf(w - bf2f(hb));
            Ahi[n * KDIM + k] = hb;
            Alo[n * KDIM + k] = lb;
        }
    }
}

// ---- pack 4 head W1 [288][256] into MFMA-B fragment-major bf16 hi/lo -------
// Bp index = ((nf*9 + ks)*64 + lane)*8 + i  holds  W[ks*32+(lane>>4)*8+i][nf*16+(lane&15)]
__global__ __launch_bounds__(256) void w1pack_k(const float* __restrict__ w0,
        const float* __restrict__ w1, const float* __restrict__ w2,
        const float* __restrict__ w3,
        ushort_t* __restrict__ Bph, ushort_t* __restrict__ Bpl) {
    int tid = blockIdx.x * 256 + threadIdx.x;       // (nf*9+ks)*64 + l
    if (tid >= 64 * 9 * 64) return;
    int l = tid & 63;
    int t = tid >> 6;
    int ks = t % 9, nf = t / 9;
    int ncol = nf * 16 + (l & 15);
    int head = ncol >> 8, c = ncol & 255;
    const float* w = head == 0 ? w0 : head == 1 ? w1 : head == 2 ? w2 : w3;
    int kbase = ks * 32 + (l >> 4) * 8;
    ushort_t hb[8], lb[8];
    #pragma unroll
    for (int i = 0; i < 8; ++i) {
        float x = w[(kbase + i) * HID + c];
        hb[i] = f2bf(x);
        lb[i] = f2bf(x - bf2f(hb[i]));
    }
    #pragma unroll
    for (int i = 0; i < 8; ++i) {
        Bph[tid * 8 + i] = hb[i];
        Bpl[tid * 8 + i] = lb[i];
    }
}

// ---- MFMA GEMM: [2304 x 288] @ [288 x 1024] (+bias, ReLU) -> hidden --------
// Split-bf16 3-product: C = Ahi*Bhi + Ahi*Blo + Alo*Bhi (~fp32 accuracy).
// Wave computes 64x64 via 4x4 mfma_f32_16x16x32_bf16 fragments, direct from L2.
__global__ __launch_bounds__(128) void gemm_k(const ushort_t* __restrict__ Ahi,
        const ushort_t* __restrict__ Alo,
        const ushort_t* __restrict__ Bph, const ushort_t* __restrict__ Bpl,
        const float* __restrict__ b1_0, const float* __restrict__ b1_1,
        const float* __restrict__ b1_2, const float* __restrict__ b1_3,
        float* __restrict__ Hout) {
    int l  = threadIdx.x & 63;
    int wv = threadIdx.x >> 6;
    int m0 = blockIdx.x * 128 + wv * 64;
    int n0 = blockIdx.y * 64;
    int r15 = l & 15, kg = l >> 4;
    f32x4 acc[4][4] = {};   // [m][n]
    const ushort_t* pah = Ahi + (m0 + r15) * KDIM + kg * 8;
    const ushort_t* pal = Alo + (m0 + r15) * KDIM + kg * 8;
    for (int ks = 0; ks < 9; ++ks) {
        bf16x8 ah[4], al[4], bh[4], bl[4];
        #pragma unroll
        for (int m = 0; m < 4; ++m) {
            ah[m] = *(const bf16x8*)(pah + m * 16 * KDIM + ks * 32);
            al[m] = *(const bf16x8*)(pal + m * 16 * KDIM + ks * 32);
        }
        #pragma unroll
        for (int n = 0; n < 4; ++n) {
            size_t off = ((size_t)((blockIdx.y * 4 + n) * 9 + ks) * 64 + l) * 8;
            bh[n] = *(const bf16x8*)(Bph + off);
            bl[n] = *(const bf16x8*)(Bpl + off);
        }
        #pragma unroll
        for (int m = 0; m < 4; ++m)
            #pragma unroll
            for (int n = 0; n < 4; ++n) {
                acc[m][n] = __builtin_amdgcn_mfma_f32_16x16x32_bf16(ah[m], bh[n], acc[m][n], 0, 0, 0);
                acc[m][n] = __builtin_amdgcn_mfma_f32_16x16x32_bf16(ah[m], bl[n], acc[m][n], 0, 0, 0);
                acc[m][n] = __builtin_amdgcn_mfma_f32_16x16x32_bf16(al[m], bh[n], acc[m][n], 0, 0, 0);
            }
    }
    // C/D layout: col = lane&15, row = (lane>>4)*4 + reg   [m89-verified]
    #pragma unroll
    for (int n = 0; n < 4; ++n) {
        int col = n0 + n * 16 + r15;
        int head = col >> 8;
        const float* bb = head == 0 ? b1_0 : head == 1 ? b1_1 : head == 2 ? b1_2 : b1_3;
        float bias = bb[col & 255];
        #pragma unroll
        for (int m = 0; m < 4; ++m)
            #pragma unroll
            for (int r = 0; r < 4; ++r) {
                int grow = m0 + m * 16 + kg * 4 + r;
                Hout[grow * NHID + col] = fmaxf(acc[m][n][r] + bias, 0.f);
            }
    }
}

// ------- per-gaussian: 8 head dots (256 each), activations, conic, bbox -----
__global__ __launch_bounds__(256) void head_k(const float* __restrict__ Hh,
        const float* __restrict__ ow2, const float* __restrict__ ob2,
        const float* __restrict__ sw2, const float* __restrict__ sb2,
        const float* __restrict__ rw2, const float* __restrict__ rb2,
        const float* __restrict__ cw2, const float* __restrict__ cb2,
        float4* __restrict__ gbox, float4* __restrict__ gdat) {
    int tid = threadIdx.x;
    int lane = tid & 63, wv = tid >> 6;
    int n = blockIdx.x * 4 + wv;
    const float* h = Hh + n * NHID;
    float s[8] = {};
    #pragma unroll
    for (int i = 0; i < 4; ++i) {
        int j = lane + 64 * i;
        float h0 = h[j], h1 = h[256 + j], h2 = h[512 + j], h3 = h[768 + j];
        s[0] = fmaf(h0, ow2[j * 2 + 0], s[0]);
        s[1] = fmaf(h0, ow2[j * 2 + 1], s[1]);
        s[2] = fmaf(h1, sw2[j * 2 + 0], s[2]);
        s[3] = fmaf(h1, sw2[j * 2 + 1], s[3]);
        s[4] = fmaf(h2, rw2[j],         s[4]);
        s[5] = fmaf(h3, cw2[j * 3 + 0], s[5]);
        s[6] = fmaf(h3, cw2[j * 3 + 1], s[6]);
        s[7] = fmaf(h3, cw2[j * 3 + 2], s[7]);
    }
    #pragma unroll
    for (int off = 32; off; off >>= 1)
        #pragma unroll
        for (int k = 0; k < 8; ++k) s[k] += __shfl_xor(s[k], off);
    if (lane == 0) {
        float o0 = s[0] + ob2[0], o1 = s[1] + ob2[1];
        float z0 = s[2] + sb2[0], z1 = s[3] + sb2[1];
        float zr = s[4] + rb2[0];
        float c0 = s[5] + cb2[0], c1 = s[6] + cb2[1], c2 = s[7] + cb2[2];
        int x = n / NXY, y = n % NXY;
        // off_factor = 2*4/192 -> offset = tanh*3*off_factor = tanh*0.125
        float ndcx = ((x + 0.5f) * (2.0f / NXY) - 1.0f) + tanhf(o0) * 0.125f;
        float ndcy = ((y + 0.5f) * (2.0f / NXY) - 1.0f) + tanhf(o1) * 0.125f;
        float cxp = 0.5f * ((ndcx + 1.0f) * HW - 1.0f);
        float cyp = 0.5f * ((ndcy + 1.0f) * HW - 1.0f);
        float sx = 8.0f / (1.0f + expf(-z0));   // sigmoid * 2 * factor
        float sy = 8.0f / (1.0f + expf(-z1));
        float rot = 6.283185307179586f / (1.0f + expf(-zr));
        float cc = cosf(rot), ss = sinf(rot);
        float sx2 = sx * sx, sy2 = sy * sy;
        float cov00 = cc * cc * sx2 + ss * ss * sy2;
        float cov01 = cc * ss * (sx2 - sy2);
        float cov11 = ss * ss * sx2 + cc * cc * sy2;
        float det = cov00 * cov11 - cov01 * cov01;
        float inv = 1.0f / det;
        float A = cov11 * inv, Bc = -cov01 * inv, Cc = cov00 * inv;
        // bbox of {alpha >= 1/255}: |dx| <= sqrt(2*tau*cov00), tau=ln255
        float rx = sqrtf(11.2f * cov00) + 1e-2f;
        float ry = sqrtf(11.2f * cov11) + 1e-2f;
        gbox[n]         = make_float4(cxp, cyp, rx, ry);
        gdat[2 * n]     = make_float4(0.5f * A, Bc, 0.5f * Cc, tanhf(c0));
        gdat[2 * n + 1] = make_float4(tanhf(c1), tanhf(c2), 0.f, 0.f);
    }
}

// --------------- render: 8x8 pixel tile, 4 waves split gaussians, culled ----
__global__ __launch_bounds__(256) void render_k(const float4* __restrict__ gbox,
                                                const float4* __restrict__ gdat,
                                                float* __restrict__ out) {
    __shared__ float4 ldsE[4][64][2];   // per-wave compacted survivor list
    __shared__ float red[4][64][3];     // cross-wave reduction
    int lane = threadIdx.x & 63;
    int wv   = threadIdx.x >> 6;
    int tx0 = blockIdx.x * 8, ty0 = blockIdx.y * 8;
    float px = (float)(tx0 + (lane & 7));
    float py = (float)(ty0 + (lane >> 3));
    float xlo = (float)tx0, xhi = (float)(tx0 + 7);
    float ylo = (float)ty0, yhi = (float)(ty0 + 7);
    float ar = 0.f, ag = 0.f, ab = 0.f;
    for (int c = wv; c < NCHUNK; c += 4) {
        int g = c * 64 + lane;
        float4 bb = gbox[g];
        bool pred = (bb.x - bb.z <= xhi) && (bb.x + bb.z >= xlo) &&
                    (bb.y - bb.w <= yhi) && (bb.y + bb.w >= ylo);
        unsigned long long m = __ballot(pred);
        int cnt = __popcll(m);
        int pos = __popcll(m & ((1ull << lane) - 1ull));
        if (pred) {
            float4 d0 = gdat[2 * g];
            float4 d1 = gdat[2 * g + 1];
            ldsE[wv][pos][0] = make_float4(bb.x, bb.y, d0.x, d0.y);  // cx cy .5A B
            ldsE[wv][pos][1] = make_float4(d0.z, d0.w, d1.x, d1.y);  // .5C r g b
        }
        __syncthreads();   // orders LDS writes vs reads (uniform trip count)
        for (int i = 0; i < cnt; ++i) {
            float4 e0 = ldsE[wv][i][0];
            float4 e1 = ldsE[wv][i][1];
            float dx = px - e0.x;
            float dy = py - e0.y;
            float sigma = fmaf(dx, fmaf(e0.z, dx, e0.w * dy), e1.x * dy * dy);
            float a = __expf(-sigma);
            a = (a >= (1.0f / 255.0f)) ? a : 0.f;
            ar = fmaf(a, e1.y, ar);
            ag = fmaf(a, e1.z, ag);
            ab = fmaf(a, e1.w, ab);
        }
        __syncthreads();
    }
    red[wv][lane][0] = ar; red[wv][lane][1] = ag; red[wv][lane][2] = ab;
    __syncthreads();
    if (wv == 0) {
        float r_ = red[0][lane][0] + red[1][lane][0] + red[2][lane][0] + red[3][lane][0];
        float g_ = red[0][lane][1] + red[1][lane][1] + red[2][lane][1] + red[3][lane][1];
        float b_ = red[0][lane][2] + red[1][lane][2] + red[2][lane][2] + red[3][lane][2];
        int pix = (ty0 + (lane >> 3)) * HW + tx0 + (lane & 7);
        out[pix]            = fminf(fmaxf(r_, 0.f), 1.f);
        out[NPIX + pix]     = fminf(fmaxf(g_, 0.f), 1.f);
        out[2 * NPIX + pix] = fminf(fmaxf(b_, 0.f), 1.f);
    }
}

extern "C" void kernel_launch(void* const* d_in, const int* in_sizes, int n_in,
                              void* d_out, int out_size, void* d_ws, size_t ws_size,
                              hipStream_t stream) {
    const float* inp = (const float*)d_in[0];
    const float* cw  = (const float*)d_in[1];
    const float* cb  = (const float*)d_in[2];
    const float* ow1 = (const float*)d_in[3];
    const float* ob1 = (const float*)d_in[4];
    const float* ow2 = (const float*)d_in[5];
    const float* ob2 = (const float*)d_in[6];
    const float* sw1 = (const float*)d_in[7];
    const float* sb1 = (const float*)d_in[8];
    const float* sw2 = (const float*)d_in[9];
    const float* sb2 = (const float*)d_in[10];
    const float* rw1 = (const float*)d_in[11];
    const float* rb1 = (const float*)d_in[12];
    const float* rw2 = (const float*)d_in[13];
    const float* rb2 = (const float*)d_in[14];
    const float* cw1 = (const float*)d_in[15];
    const float* cb1 = (const float*)d_in[16];
    const float* cw2 = (const float*)d_in[17];
    const float* cb2 = (const float*)d_in[18];

    float* ws = (float*)d_ws;
    float*    feat = ws;                               // 73728 f
    float*    hid  = ws + 73728;                       // 2359296 f
    float4*   gbox = (float4*)(ws + 2433024);          // 2304 float4
    float4*   gdat = (float4*)(ws + 2442240);          // 4608 float4
    ushort_t* Ahi  = (ushort_t*)(ws + 2460672);        // 663552 us
    ushort_t* Alo  = (ushort_t*)(ws + 2792448);        // 663552 us
    ushort_t* Bph  = (ushort_t*)(ws + 3124224);        // 294912 us
    ushort_t* Bpl  = (ushort_t*)(ws + 3271680);        // 294912 us
    float* out = (float*)d_out;

    hipLaunchKernelGGL(conv_k, dim3(288), dim3(256), 0, stream, inp, cw, cb, feat);
    hipLaunchKernelGGL(ln_k, dim3(NG), dim3(64), 0, stream, feat, Ahi, Alo);
    hipLaunchKernelGGL(w1pack_k, dim3(144), dim3(256), 0, stream,
                       ow1, sw1, rw1, cw1, Bph, Bpl);
    hipLaunchKernelGGL(gemm_k, dim3(18, 16), dim3(128), 0, stream,
                       Ahi, Alo, Bph, Bpl, ob1, sb1, rb1, cb1, hid);
    hipLaunchKernelGGL(head_k, dim3(576), dim3(256), 0, stream,
                       hid, ow2, ob2, sw2, sb2, rw2, rb2, cw2, cb2, gbox, gdat);
    hipLaunchKernelGGL(render_k, dim3(24, 24), dim3(256), 0, stream, gbox, gdat, out);
}

// Round 4
// 47.297 us; speedup vs baseline: 4.8469x; 1.1246x over previous
//
#include <hip/hip_runtime.h>

// Problem constants (setup_inputs is fixed: 48x48 input, 192x192 output, factor=4)
#define NXY   48
#define NG    2304      // 48*48 gaussians
#define CFE   32        // conv output channels
#define KDIM  288       // 32*9 unfolded feature dim
#define HID   256
#define NHID  1024      // 4 heads * 256
#define HW    192
#define NPIX  (HW*HW)   // 36864
#define NCHUNK (NG/64)  // 36 gaussian chunks of 64

typedef __bf16 bf16x8 __attribute__((ext_vector_type(8)));
typedef float  f32x4  __attribute__((ext_vector_type(4)));
typedef unsigned short ushort_t;
typedef unsigned int   uint_t;

__device__ __forceinline__ ushort_t f2bf(float x) {          // RNE float->bf16 bits
    uint_t u = __float_as_uint(x);
    uint_t r = u + 0x7FFFu + ((u >> 16) & 1u);
    return (ushort_t)(r >> 16);
}
__device__ __forceinline__ float bf2f(ushort_t h) {
    return __uint_as_float(((uint_t)h) << 16);
}

// ---------------- conv 3x3 SAME, NCHW, correlation (lax conv) ----------------
__global__ __launch_bounds__(256) void conv_k(const float* __restrict__ inp,
                                              const float* __restrict__ cw,
                                              const float* __restrict__ cb,
                                              float* __restrict__ feat) {
    int idx = blockIdx.x * 256 + threadIdx.x;   // c*2304 + h*48 + w
    if (idx >= CFE * NXY * NXY) return;
    int w = idx % NXY, h = (idx / NXY) % NXY, o = idx / (NXY * NXY);
    float acc = cb[o];
    #pragma unroll
    for (int i = 0; i < 3; ++i) {
        #pragma unroll
        for (int kh = 0; kh < 3; ++kh) {
            int hh = h + kh - 1;
            if (hh < 0 || hh >= NXY) continue;
            #pragma unroll
            for (int kw = 0; kw < 3; ++kw) {
                int ww = w + kw - 1;
                if (ww < 0 || ww >= NXY) continue;
                acc = fmaf(inp[(i * NXY + hh) * NXY + ww],
                           cw[((o * 3 + i) * 3 + kh) * 3 + kw], acc);
            }
        }
    }
    feat[idx] = acc;
}

// --------- unfold 3x3 + LayerNorm over 288 -> split bf16 (hi, lo) -----------
// feature[n=(x,y)][c*9+ki*3+kj] = feat[c][h=y+kj-1][w=x+ki-1] (zero-padded)
__global__ __launch_bounds__(64) void ln_k(const float* __restrict__ feat,
                                           ushort_t* __restrict__ Ahi,
                                           ushort_t* __restrict__ Alo) {
    int n = blockIdx.x;
    int lane = threadIdx.x;
    int x = n / NXY, y = n % NXY;
    float v[5];
    float sum = 0.f, sq = 0.f;
    #pragma unroll
    for (int i = 0; i < 5; ++i) {
        int k = lane + 64 * i;
        float val = 0.f;
        if (k < KDIM) {
            int c = k / 9, r = k % 9, ki = r / 3, kj = r % 3;
            int hh = y + kj - 1, ww = x + ki - 1;
            if (hh >= 0 && hh < NXY && ww >= 0 && ww < NXY)
                val = feat[(c * NXY + hh) * NXY + ww];
        }
        v[i] = val; sum += val; sq = fmaf(val, val, sq);
    }
    #pragma unroll
    for (int off = 32; off; off >>= 1) {
        sum += __shfl_xor(sum, off);
        sq  += __shfl_xor(sq,  off);
    }
    float mean = sum * (1.0f / KDIM);
    float var  = sq * (1.0f / KDIM) - mean * mean;
    float rstd = rsqrtf(var + 1e-5f);
    #pragma unroll
    for (int i = 0; i < 5; ++i) {
        int k = lane + 64 * i;
        if (k < KDIM) {
            float w = (v[i] - mean) * rstd;
            ushort_t hb = f2bf(w);
            ushort_t lb = f2bf(w - bf2f(hb));
            Ahi[n * KDIM + k] = hb;
            Alo[n * KDIM + k] = lb;
        }
    }
}

// ---- pack 4 head W1 [288][256] into MFMA-B fragment-major bf16 hi/lo -------
// Bp index = ((nf*9 + ks)*64 + lane)*8 + i  holds  W[ks*32+(lane>>4)*8+i][nf*16+(lane&15)]
__global__ __launch_bounds__(256) void w1pack_k(const float* __restrict__ w0,
        const float* __restrict__ w1, const float* __restrict__ w2,
        const float* __restrict__ w3,
        ushort_t* __restrict__ Bph, ushort_t* __restrict__ Bpl) {
    int tid = blockIdx.x * 256 + threadIdx.x;       // (nf*9+ks)*64 + l
    if (tid >= 64 * 9 * 64) return;
    int l = tid & 63;
    int t = tid >> 6;
    int ks = t % 9, nf = t / 9;
    int ncol = nf * 16 + (l & 15);
    int head = ncol >> 8, c = ncol & 255;
    const float* w = head == 0 ? w0 : head == 1 ? w1 : head == 2 ? w2 : w3;
    int kbase = ks * 32 + (l >> 4) * 8;
    ushort_t hb[8], lb[8];
    #pragma unroll
    for (int i = 0; i < 8; ++i) {
        float x = w[(kbase + i) * HID + c];
        hb[i] = f2bf(x);
        lb[i] = f2bf(x - bf2f(hb[i]));
    }
    #pragma unroll
    for (int i = 0; i < 8; ++i) {
        Bph[tid * 8 + i] = hb[i];
        Bpl[tid * 8 + i] = lb[i];
    }
}

// ---- MFMA GEMM: [2304 x 288] @ [288 x 1024] (+bias, ReLU) -> hidden --------
// Split-bf16 3-product: C = Ahi*Bhi + Ahi*Blo + Alo*Bhi (~fp32 accuracy).
// v2: 32x32 output per wave (2x2 frags), 2304 waves = 9 waves/CU for latency
// hiding (576-wave v1 was <1 wave/SIMD -> L2 latency fully exposed).
__global__ __launch_bounds__(256) void gemm_k(const ushort_t* __restrict__ Ahi,
        const ushort_t* __restrict__ Alo,
        const ushort_t* __restrict__ Bph, const ushort_t* __restrict__ Bpl,
        const float* __restrict__ b1_0, const float* __restrict__ b1_1,
        const float* __restrict__ b1_2, const float* __restrict__ b1_3,
        float* __restrict__ Hout) {
    int l   = threadIdx.x & 63;
    int wv  = threadIdx.x >> 6;
    int m0  = blockIdx.x * 64 + (wv >> 1) * 32;     // 32-row wave tile
    int nf0 = blockIdx.y * 4 + (wv & 1) * 2;        // base 16-col fragment idx
    int r15 = l & 15, kg = l >> 4;
    f32x4 acc[2][2] = {};   // [m][n]
    const ushort_t* pah = Ahi + (m0 + r15) * KDIM + kg * 8;
    const ushort_t* pal = Alo + (m0 + r15) * KDIM + kg * 8;
    #pragma unroll 3
    for (int ks = 0; ks < 9; ++ks) {
        bf16x8 ah[2], al[2], bh[2], bl[2];
        #pragma unroll
        for (int m = 0; m < 2; ++m) {
            ah[m] = *(const bf16x8*)(pah + m * 16 * KDIM + ks * 32);
            al[m] = *(const bf16x8*)(pal + m * 16 * KDIM + ks * 32);
        }
        #pragma unroll
        for (int n = 0; n < 2; ++n) {
            size_t off = ((size_t)((nf0 + n) * 9 + ks) * 64 + l) * 8;
            bh[n] = *(const bf16x8*)(Bph + off);
            bl[n] = *(const bf16x8*)(Bpl + off);
        }
        #pragma unroll
        for (int m = 0; m < 2; ++m)
            #pragma unroll
            for (int n = 0; n < 2; ++n) {
                acc[m][n] = __builtin_amdgcn_mfma_f32_16x16x32_bf16(ah[m], bh[n], acc[m][n], 0, 0, 0);
                acc[m][n] = __builtin_amdgcn_mfma_f32_16x16x32_bf16(ah[m], bl[n], acc[m][n], 0, 0, 0);
                acc[m][n] = __builtin_amdgcn_mfma_f32_16x16x32_bf16(al[m], bh[n], acc[m][n], 0, 0, 0);
            }
    }
    // C/D layout: col = lane&15, row = (lane>>4)*4 + reg   [m89-verified]
    #pragma unroll
    for (int n = 0; n < 2; ++n) {
        int col = (nf0 + n) * 16 + r15;
        int head = col >> 8;
        const float* bb = head == 0 ? b1_0 : head == 1 ? b1_1 : head == 2 ? b1_2 : b1_3;
        float bias = bb[col & 255];
        #pragma unroll
        for (int m = 0; m < 2; ++m)
            #pragma unroll
            for (int r = 0; r < 4; ++r) {
                int grow = m0 + m * 16 + kg * 4 + r;
                Hout[grow * NHID + col] = fmaxf(acc[m][n][r] + bias, 0.f);
            }
    }
}

// ------- per-gaussian: 8 head dots (256 each), activations, conic, bbox -----
__global__ __launch_bounds__(256) void head_k(const float* __restrict__ Hh,
        const float* __restrict__ ow2, const float* __restrict__ ob2,
        const float* __restrict__ sw2, const float* __restrict__ sb2,
        const float* __restrict__ rw2, const float* __restrict__ rb2,
        const float* __restrict__ cw2, const float* __restrict__ cb2,
        float4* __restrict__ gbox, float4* __restrict__ gdat) {
    int tid = threadIdx.x;
    int lane = tid & 63, wv = tid >> 6;
    int n = blockIdx.x * 4 + wv;
    const float* h = Hh + n * NHID;
    float s[8] = {};
    #pragma unroll
    for (int i = 0; i < 4; ++i) {
        int j = lane + 64 * i;
        float h0 = h[j], h1 = h[256 + j], h2 = h[512 + j], h3 = h[768 + j];
        s[0] = fmaf(h0, ow2[j * 2 + 0], s[0]);
        s[1] = fmaf(h0, ow2[j * 2 + 1], s[1]);
        s[2] = fmaf(h1, sw2[j * 2 + 0], s[2]);
        s[3] = fmaf(h1, sw2[j * 2 + 1], s[3]);
        s[4] = fmaf(h2, rw2[j],         s[4]);
        s[5] = fmaf(h3, cw2[j * 3 + 0], s[5]);
        s[6] = fmaf(h3, cw2[j * 3 + 1], s[6]);
        s[7] = fmaf(h3, cw2[j * 3 + 2], s[7]);
    }
    #pragma unroll
    for (int off = 32; off; off >>= 1)
        #pragma unroll
        for (int k = 0; k < 8; ++k) s[k] += __shfl_xor(s[k], off);
    if (lane == 0) {
        float o0 = s[0] + ob2[0], o1 = s[1] + ob2[1];
        float z0 = s[2] + sb2[0], z1 = s[3] + sb2[1];
        float zr = s[4] + rb2[0];
        float c0 = s[5] + cb2[0], c1 = s[6] + cb2[1], c2 = s[7] + cb2[2];
        int x = n / NXY, y = n % NXY;
        // off_factor = 2*4/192 -> offset = tanh*3*off_factor = tanh*0.125
        float ndcx = ((x + 0.5f) * (2.0f / NXY) - 1.0f) + tanhf(o0) * 0.125f;
        float ndcy = ((y + 0.5f) * (2.0f / NXY) - 1.0f) + tanhf(o1) * 0.125f;
        float cxp = 0.5f * ((ndcx + 1.0f) * HW - 1.0f);
        float cyp = 0.5f * ((ndcy + 1.0f) * HW - 1.0f);
        float sx = 8.0f / (1.0f + expf(-z0));   // sigmoid * 2 * factor
        float sy = 8.0f / (1.0f + expf(-z1));
        float rot = 6.283185307179586f / (1.0f + expf(-zr));
        float cc = cosf(rot), ss = sinf(rot);
        float sx2 = sx * sx, sy2 = sy * sy;
        float cov00 = cc * cc * sx2 + ss * ss * sy2;
        float cov01 = cc * ss * (sx2 - sy2);
        float cov11 = ss * ss * sx2 + cc * cc * sy2;
        float det = cov00 * cov11 - cov01 * cov01;
        float inv = 1.0f / det;
        float A = cov11 * inv, Bc = -cov01 * inv, Cc = cov00 * inv;
        // bbox of {alpha >= 1/255}: |dx| <= sqrt(2*tau*cov00), tau=ln255
        float rx = sqrtf(11.2f * cov00) + 1e-2f;
        float ry = sqrtf(11.2f * cov11) + 1e-2f;
        gbox[n]         = make_float4(cxp, cyp, rx, ry);
        gdat[2 * n]     = make_float4(0.5f * A, Bc, 0.5f * Cc, tanhf(c0));
        gdat[2 * n + 1] = make_float4(tanhf(c1), tanhf(c2), 0.f, 0.f);
    }
}

// --------------- render: 8x8 pixel tile, 4 waves split gaussians, culled ----
__global__ __launch_bounds__(256) void render_k(const float4* __restrict__ gbox,
                                                const float4* __restrict__ gdat,
                                                float* __restrict__ out) {
    __shared__ float4 ldsE[4][64][2];   // per-wave compacted survivor list
    __shared__ float red[4][64][3];     // cross-wave reduction
    int lane = threadIdx.x & 63;
    int wv   = threadIdx.x >> 6;
    int tx0 = blockIdx.x * 8, ty0 = blockIdx.y * 8;
    float px = (float)(tx0 + (lane & 7));
    float py = (float)(ty0 + (lane >> 3));
    float xlo = (float)tx0, xhi = (float)(tx0 + 7);
    float ylo = (float)ty0, yhi = (float)(ty0 + 7);
    float ar = 0.f, ag = 0.f, ab = 0.f;
    for (int c = wv; c < NCHUNK; c += 4) {
        int g = c * 64 + lane;
        float4 bb = gbox[g];
        bool pred = (bb.x - bb.z <= xhi) && (bb.x + bb.z >= xlo) &&
                    (bb.y - bb.w <= yhi) && (bb.y + bb.w >= ylo);
        unsigned long long m = __ballot(pred);
        int cnt = __popcll(m);
        int pos = __popcll(m & ((1ull << lane) - 1ull));
        if (pred) {
            float4 d0 = gdat[2 * g];
            float4 d1 = gdat[2 * g + 1];
            ldsE[wv][pos][0] = make_float4(bb.x, bb.y, d0.x, d0.y);  // cx cy .5A B
            ldsE[wv][pos][1] = make_float4(d0.z, d0.w, d1.x, d1.y);  // .5C r g b
        }
        __syncthreads();   // orders LDS writes vs reads (uniform trip count)
        for (int i = 0; i < cnt; ++i) {
            float4 e0 = ldsE[wv][i][0];
            float4 e1 = ldsE[wv][i][1];
            float dx = px - e0.x;
            float dy = py - e0.y;
            float sigma = fmaf(dx, fmaf(e0.z, dx, e0.w * dy), e1.x * dy * dy);
            float a = __expf(-sigma);
            a = (a >= (1.0f / 255.0f)) ? a : 0.f;
            ar = fmaf(a, e1.y, ar);
            ag = fmaf(a, e1.z, ag);
            ab = fmaf(a, e1.w, ab);
        }
        __syncthreads();
    }
    red[wv][lane][0] = ar; red[wv][lane][1] = ag; red[wv][lane][2] = ab;
    __syncthreads();
    if (wv == 0) {
        float r_ = red[0][lane][0] + red[1][lane][0] + red[2][lane][0] + red[3][lane][0];
        float g_ = red[0][lane][1] + red[1][lane][1] + red[2][lane][1] + red[3][lane][1];
        float b_ = red[0][lane][2] + red[1][lane][2] + red[2][lane][2] + red[3][lane][2];
        int pix = (ty0 + (lane >> 3)) * HW + tx0 + (lane & 7);
        out[pix]            = fminf(fmaxf(r_, 0.f), 1.f);
        out[NPIX + pix]     = fminf(fmaxf(g_, 0.f), 1.f);
        out[2 * NPIX + pix] = fminf(fmaxf(b_, 0.f), 1.f);
    }
}

extern "C" void kernel_launch(void* const* d_in, const int* in_sizes, int n_in,
                              void* d_out, int out_size, void* d_ws, size_t ws_size,
                              hipStream_t stream) {
    const float* inp = (const float*)d_in[0];
    const float* cw  = (const float*)d_in[1];
    const float* cb  = (const float*)d_in[2];
    const float* ow1 = (const float*)d_in[3];
    const float* ob1 = (const float*)d_in[4];
    const float* ow2 = (const float*)d_in[5];
    const float* ob2 = (const float*)d_in[6];
    const float* sw1 = (const float*)d_in[7];
    const float* sb1 = (const float*)d_in[8];
    const float* sw2 = (const float*)d_in[9];
    const float* sb2 = (const float*)d_in[10];
    const float* rw1 = (const float*)d_in[11];
    const float* rb1 = (const float*)d_in[12];
    const float* rw2 = (const float*)d_in[13];
    const float* rb2 = (const float*)d_in[14];
    const float* cw1 = (const float*)d_in[15];
    const float* cb1 = (const float*)d_in[16];
    const float* cw2 = (const float*)d_in[17];
    const float* cb2 = (const float*)d_in[18];

    float* ws = (float*)d_ws;
    float*    feat = ws;                               // 73728 f
    float*    hid  = ws + 73728;                       // 2359296 f
    float4*   gbox = (float4*)(ws + 2433024);          // 2304 float4
    float4*   gdat = (float4*)(ws + 2442240);          // 4608 float4
    ushort_t* Ahi  = (ushort_t*)(ws + 2460672);        // 663552 us
    ushort_t* Alo  = (ushort_t*)(ws + 2792448);        // 663552 us
    ushort_t* Bph  = (ushort_t*)(ws + 3124224);        // 294912 us
    ushort_t* Bpl  = (ushort_t*)(ws + 3271680);        // 294912 us
    float* out = (float*)d_out;

    hipLaunchKernelGGL(conv_k, dim3(288), dim3(256), 0, stream, inp, cw, cb, feat);
    hipLaunchKernelGGL(ln_k, dim3(NG), dim3(64), 0, stream, feat, Ahi, Alo);
    hipLaunchKernelGGL(w1pack_k, dim3(144), dim3(256), 0, stream,
                       ow1, sw1, rw1, cw1, Bph, Bpl);
    hipLaunchKernelGGL(gemm_k, dim3(36, 16), dim3(256), 0, stream,
                       Ahi, Alo, Bph, Bpl, ob1, sb1, rb1, cb1, hid);
    hipLaunchKernelGGL(head_k, dim3(576), dim3(256), 0, stream,
                       hid, ow2, ob2, sw2, sb2, rw2, rb2, cw2, cb2, gbox, gdat);
    hipLaunchKernelGGL(render_k, dim3(24, 24), dim3(256), 0, stream, gbox, gdat, out);
}